// Round 2
// baseline (17807.962 us; speedup 1.0000x reference)
//
#include <hip/hip_runtime.h>

// ---------------------------------------------------------------------------
// CoLA forward on MI355X — round 2: fp64 tile-accumulation on the
// actionness-critical chain (embed conv -> cas -> actionness) to make the
// top-k selections bit-match the numpy reference's ordering.
// ---------------------------------------------------------------------------

static __device__ __forceinline__ float leaky_f(float x) { return x >= 0.f ? x : 0.2f * x; }

// ---------- pack (N,KC,taps) -> (taps,N,KC) ----------
__global__ __launch_bounds__(256) void pack_w_k(const float* __restrict__ src,
                                                float* __restrict__ dst,
                                                int N, int KC, int taps) {
  long total = (long)N * KC * taps;
  long i = (long)blockIdx.x * 256 + threadIdx.x;
  if (i >= total) return;
  long nk = (long)N * KC;
  int tap = (int)(i / nk);
  long rem = i - (long)tap * nk;
  int n = (int)(rem / KC);
  int k = (int)(rem - (long)n * KC);
  dst[i] = src[((long)n * KC + k) * taps + tap];
}

// ---------- generic 64x64 fp32 GEMM / k3-conv:  C = act(A*B^T + bias) ----------
// DACC=1: per-K-tile fp32 partial added into fp64 accumulator (accuracy for
// the selection-critical path).
template <int DACC>
__global__ __launch_bounds__(256) void gemm64_k(
    const float* __restrict__ A, const float* __restrict__ Bw,
    const float* __restrict__ bias, float* __restrict__ C,
    int M, int N, int KC, int taps, int shift_base,
    int a_grp, long a_bstride, int c_grp, long c_bstride, int act) {
  __shared__ __align__(16) float As[16][68];
  __shared__ __align__(16) float Bs[16][68];
  int tid = threadIdx.x;
  int n0 = blockIdx.x * 64, m0 = blockIdx.y * 64;
  int tx = tid & 15, ty = tid >> 4;
  int row_l = tid >> 2;
  int kq = (tid & 3) << 2;
  float accf[4][4] = {{0.f}};
  double accd[4][4];
  if (DACC) {
#pragma unroll
    for (int i = 0; i < 4; ++i)
#pragma unroll
      for (int j = 0; j < 4; ++j) accd[i][j] = 0.0;
  }
  int tpt = KC >> 4;           // K-tiles per tap
  int nkt = tpt * taps;
  int am = m0 + row_l;
  int agrp = 0, ar = 0;
  if (am < M) { agrp = am / a_grp; ar = am - agrp * a_grp; }
  int bn = n0 + row_l;
  for (int kt = 0; kt < nkt; ++kt) {
    int tap = kt / tpt;
    int k0 = (kt - tap * tpt) << 4;
    float4 av = make_float4(0.f, 0.f, 0.f, 0.f);
    float4 bv = make_float4(0.f, 0.f, 0.f, 0.f);
    if (am < M) {
      int rr = ar + tap + shift_base;
      if (rr >= 0 && rr < a_grp)
        av = *(const float4*)(A + (long)agrp * a_bstride + (long)rr * KC + (k0 + kq));
    }
    if (bn < N)
      bv = *(const float4*)(Bw + ((long)tap * N + bn) * KC + (k0 + kq));
    __syncthreads();
    As[kq + 0][row_l] = av.x; As[kq + 1][row_l] = av.y;
    As[kq + 2][row_l] = av.z; As[kq + 3][row_l] = av.w;
    Bs[kq + 0][row_l] = bv.x; Bs[kq + 1][row_l] = bv.y;
    Bs[kq + 2][row_l] = bv.z; Bs[kq + 3][row_l] = bv.w;
    __syncthreads();
    float tile[4][4];
    if (DACC) {
#pragma unroll
      for (int i = 0; i < 4; ++i)
#pragma unroll
        for (int j = 0; j < 4; ++j) tile[i][j] = 0.f;
    }
#pragma unroll
    for (int k = 0; k < 16; ++k) {
      float4 a4 = *(const float4*)&As[k][ty << 2];
      float4 b4 = *(const float4*)&Bs[k][tx << 2];
      float ar4[4] = {a4.x, a4.y, a4.z, a4.w};
      float br4[4] = {b4.x, b4.y, b4.z, b4.w};
#pragma unroll
      for (int i = 0; i < 4; ++i)
#pragma unroll
        for (int j = 0; j < 4; ++j) {
          if (DACC) tile[i][j] = fmaf(ar4[i], br4[j], tile[i][j]);
          else      accf[i][j] = fmaf(ar4[i], br4[j], accf[i][j]);
        }
    }
    if (DACC) {
#pragma unroll
      for (int i = 0; i < 4; ++i)
#pragma unroll
        for (int j = 0; j < 4; ++j) accd[i][j] += (double)tile[i][j];
    }
  }
#pragma unroll
  for (int i = 0; i < 4; ++i) {
    int m = m0 + (ty << 2) + i;
    if (m >= M) continue;
    int grp = m / c_grp, r = m - grp * c_grp;
    float* crow = C + (long)grp * c_bstride + (long)r * N;
#pragma unroll
    for (int j = 0; j < 4; ++j) {
      int n = n0 + (tx << 2) + j;
      if (n >= N) continue;
      float v = DACC ? (float)accd[i][j] : accf[i][j];
      if (bias) v += bias[n];
      if (act == 1) v = fmaxf(v, 0.f);
      else if (act == 2) v = leaky_f(v);
      crow[n] = v;
    }
  }
}

// ---------- 32x32 fp32 GEMM variant (small N), K-tile 32 ----------
template <int DACC>
__global__ __launch_bounds__(256) void gemm32_k(
    const float* __restrict__ A, const float* __restrict__ Bw,
    const float* __restrict__ bias, float* __restrict__ C,
    int M, int N, int KC, int taps, int shift_base,
    int a_grp, long a_bstride, int c_grp, long c_bstride, int act) {
  __shared__ __align__(16) float As[32][36];
  __shared__ __align__(16) float Bs[32][36];
  int tid = threadIdx.x;
  int n0 = blockIdx.x * 32, m0 = blockIdx.y * 32;
  int tx = tid & 15, ty = tid >> 4;
  int row_l = tid >> 3;          // 0..31
  int kq = (tid & 7) << 2;       // 0..28
  float accf[2][2] = {{0.f}};
  double accd[2][2];
  if (DACC) { accd[0][0] = accd[0][1] = accd[1][0] = accd[1][1] = 0.0; }
  int tpt = KC >> 5;
  int nkt = tpt * taps;
  int am = m0 + row_l;
  int agrp = 0, ar = 0;
  if (am < M) { agrp = am / a_grp; ar = am - agrp * a_grp; }
  int bn = n0 + row_l;
  for (int kt = 0; kt < nkt; ++kt) {
    int tap = kt / tpt;
    int k0 = (kt - tap * tpt) << 5;
    float4 av = make_float4(0.f, 0.f, 0.f, 0.f);
    float4 bv = make_float4(0.f, 0.f, 0.f, 0.f);
    if (am < M) {
      int rr = ar + tap + shift_base;
      if (rr >= 0 && rr < a_grp)
        av = *(const float4*)(A + (long)agrp * a_bstride + (long)rr * KC + (k0 + kq));
    }
    if (bn < N)
      bv = *(const float4*)(Bw + ((long)tap * N + bn) * KC + (k0 + kq));
    __syncthreads();
    As[kq + 0][row_l] = av.x; As[kq + 1][row_l] = av.y;
    As[kq + 2][row_l] = av.z; As[kq + 3][row_l] = av.w;
    Bs[kq + 0][row_l] = bv.x; Bs[kq + 1][row_l] = bv.y;
    Bs[kq + 2][row_l] = bv.z; Bs[kq + 3][row_l] = bv.w;
    __syncthreads();
    float tile[2][2] = {{0.f, 0.f}, {0.f, 0.f}};
#pragma unroll
    for (int k = 0; k < 32; ++k) {
      float2 a2 = *(const float2*)&As[k][ty << 1];
      float2 b2 = *(const float2*)&Bs[k][tx << 1];
      if (DACC) {
        tile[0][0] = fmaf(a2.x, b2.x, tile[0][0]);
        tile[0][1] = fmaf(a2.x, b2.y, tile[0][1]);
        tile[1][0] = fmaf(a2.y, b2.x, tile[1][0]);
        tile[1][1] = fmaf(a2.y, b2.y, tile[1][1]);
      } else {
        accf[0][0] = fmaf(a2.x, b2.x, accf[0][0]);
        accf[0][1] = fmaf(a2.x, b2.y, accf[0][1]);
        accf[1][0] = fmaf(a2.y, b2.x, accf[1][0]);
        accf[1][1] = fmaf(a2.y, b2.y, accf[1][1]);
      }
    }
    if (DACC) {
      accd[0][0] += (double)tile[0][0]; accd[0][1] += (double)tile[0][1];
      accd[1][0] += (double)tile[1][0]; accd[1][1] += (double)tile[1][1];
    }
  }
#pragma unroll
  for (int i = 0; i < 2; ++i) {
    int m = m0 + (ty << 1) + i;
    if (m >= M) continue;
    int grp = m / c_grp, r = m - grp * c_grp;
    float* crow = C + (long)grp * c_bstride + (long)r * N;
#pragma unroll
    for (int j = 0; j < 2; ++j) {
      int n = n0 + (tx << 1) + j;
      if (n >= N) continue;
      float v = DACC ? (float)accd[i][j] : accf[i][j];
      if (bias) v += bias[n];
      if (act == 1) v = fmaxf(v, 0.f);
      else if (act == 2) v = leaky_f(v);
      crow[n] = v;
    }
  }
}

// ---------- actionness = sum over 20 classes (fp64 accumulate) ----------
__global__ __launch_bounds__(256) void actionness_k(const float* __restrict__ cas,
                                                    float* __restrict__ act) {
  int p = blockIdx.x * 256 + threadIdx.x;
  if (p >= 16 * 750) return;
  double s = 0.0;
#pragma unroll
  for (int c = 0; c < 20; ++c) s += (double)cas[(long)p * 20 + c];
  act[p] = (float)s;
}

// ---------- a2: two 1-channel k3 convs + relu ----------
__global__ __launch_bounds__(256) void a2_k(const float* __restrict__ act,
                                            const float* __restrict__ tf1w, const float* __restrict__ tf1b,
                                            const float* __restrict__ tf2w, const float* __restrict__ tf2b,
                                            float* __restrict__ a2out) {
  __shared__ float s0[752];
  __shared__ float s1[752];
  int b = blockIdx.x, tid = threadIdx.x;
  for (int i = tid; i < 752; i += 256) { s0[i] = 0.f; s1[i] = 0.f; }
  __syncthreads();
  for (int t = tid; t < 750; t += 256) s0[t + 1] = act[b * 750 + t];
  __syncthreads();
  float w0 = tf1w[0], w1 = tf1w[1], w2 = tf1w[2], bb1 = tf1b[0];
  for (int t = tid; t < 750; t += 256)
    s1[t + 1] = fmaxf(w0 * s0[t] + w1 * s0[t + 1] + w2 * s0[t + 2] + bb1, 0.f);
  __syncthreads();
  float u0 = tf2w[0], u1 = tf2w[1], u2 = tf2w[2], bb2 = tf2b[0];
  for (int t = tid; t < 750; t += 256)
    a2out[b * 750 + t] = fmaxf(u0 * s1[t] + u1 * s1[t + 1] + u2 * s1[t + 2] + bb2, 0.f);
}

// ---------- bitonic top-k (stable: key = score_bits<<32 | ~idx, descending) ----------
__global__ __launch_bounds__(256) void sort_topk_k(const float* __restrict__ scores,
                                                   int* __restrict__ out_idx, int K,
                                                   float* __restrict__ out_med,
                                                   float* __restrict__ out_mx) {
  __shared__ unsigned long long keys[1024];
  int b = blockIdx.x, tid = threadIdx.x;
  for (int i = tid; i < 1024; i += 256) {
    unsigned long long kv = 0ull;
    if (i < 750) {
      unsigned int bits = __float_as_uint(scores[b * 750 + i]);
      kv = ((unsigned long long)bits << 32) | (unsigned long long)(0xFFFFFFFFu - (unsigned)i);
    }
    keys[i] = kv;
  }
  __syncthreads();
  for (int k = 2; k <= 1024; k <<= 1) {
    for (int j = k >> 1; j > 0; j >>= 1) {
      for (int i = tid; i < 1024; i += 256) {
        int ixj = i ^ j;
        if (ixj > i) {
          unsigned long long a = keys[i], c = keys[ixj];
          bool sw = ((i & k) == 0) ? (a < c) : (a > c);   // overall descending
          if (sw) { keys[i] = c; keys[ixj] = a; }
        }
      }
      __syncthreads();
    }
  }
  for (int i = tid; i < K; i += 256)
    out_idx[b * K + i] = (int)(0xFFFFFFFFu - (unsigned int)(keys[i] & 0xFFFFFFFFull));
  if (tid == 0) {
    if (out_mx) out_mx[b] = __uint_as_float((unsigned int)(keys[0] >> 32));
    if (out_med) {
      float v1 = __uint_as_float((unsigned int)(keys[374] >> 32));
      float v2 = __uint_as_float((unsigned int)(keys[375] >> 32));
      out_med[b] = 0.5f * (v1 + v2);
    }
  }
}

// ---------- act_rev + binary morphology scores ----------
__global__ __launch_bounds__(256) void morph_k(const float* __restrict__ act,
                                               const float* __restrict__ med,
                                               const float* __restrict__ mxv,
                                               float* __restrict__ arev,
                                               float* __restrict__ hsa,
                                               float* __restrict__ hsb) {
  __shared__ float ab[756];   // ab[t+3] = abin[t], 3-wide zero margins
  int b = blockIdx.x, tid = threadIdx.x;
  float m = med[b], M = mxv[b];
  for (int i = tid; i < 756; i += 256) ab[i] = 0.f;
  __syncthreads();
  for (int t = tid; t < 750; t += 256) {
    float a = act[b * 750 + t];
    ab[t + 3] = (a > m) ? 1.f : 0.f;
    arev[b * 750 + t] = M - a;
  }
  __syncthreads();
  for (int t = tid; t < 750; t += 256) {
    float e3 = fminf(ab[t + 2], fminf(ab[t + 3], ab[t + 4]));                       // [t-1,t+1]
    float e6 = fminf(fminf(ab[t], ab[t + 1]),
                     fminf(fminf(ab[t + 2], ab[t + 3]), fminf(ab[t + 4], ab[t + 5]))); // [t-3,t+2]
    float d3 = fmaxf(ab[t + 2], fmaxf(ab[t + 3], ab[t + 4]));                       // [t-1,t+1]
    float d6 = fmaxf(fmaxf(ab[t + 1], ab[t + 2]),
                     fmaxf(fmaxf(ab[t + 3], ab[t + 4]), fmaxf(ab[t + 5], ab[t + 6]))); // [t-2,t+3]
    float a = act[b * 750 + t];
    hsa[b * 750 + t] = a * (e3 - e6);
    hsb[b * 750 + t] = a * (d6 - d3);
  }
}

// ---------- gather embedding rows by index ----------
__global__ __launch_bounds__(256) void gather_k(const float* __restrict__ emb,
                                                const int* __restrict__ idx,
                                                float* __restrict__ dst, int K) {
  int blk = blockIdx.x;
  int b = blk / K, i = blk - b * K;
  int t = idx[b * K + i];
  const float4* src = (const float4*)(emb + ((long)(b * 750 + t)) * 2048);
  float4* d = (float4*)(dst + (long)blk * 2048);
  for (int u = threadIdx.x; u < 512; u += 256) d[u] = src[u];
}

// ---------- video scores: per (b,c) mean of top-150 of cas[b,:,c] ----------
__global__ __launch_bounds__(256) void vtop_k(const float* __restrict__ cas,
                                              float* __restrict__ s) {
  __shared__ float v[1024];
  int b = blockIdx.x / 20, c = blockIdx.x - b * 20;
  int tid = threadIdx.x;
  for (int i = tid; i < 1024; i += 256)
    v[i] = (i < 750) ? cas[((long)(b * 750 + i)) * 20 + c] : -1.f;   // cas>=0, pads last
  __syncthreads();
  for (int k = 2; k <= 1024; k <<= 1) {
    for (int j = k >> 1; j > 0; j >>= 1) {
      for (int i = tid; i < 1024; i += 256) {
        int ixj = i ^ j;
        if (ixj > i) {
          float a = v[i], cc = v[ixj];
          bool sw = ((i & k) == 0) ? (a < cc) : (a > cc);
          if (sw) { v[i] = cc; v[ixj] = a; }
        }
      }
      __syncthreads();
    }
  }
  if (tid == 0) {
    float sum = 0.f;
    for (int i = 0; i < 150; ++i) sum += v[i];
    s[b * 20 + c] = sum / 150.f;
  }
}

__global__ __launch_bounds__(64) void softmax20_k(const float* __restrict__ s,
                                                  float* __restrict__ out) {
  int b = blockIdx.x;
  if (threadIdx.x != 0) return;
  float mx = -3.4e38f;
  for (int c = 0; c < 20; ++c) mx = fmaxf(mx, s[b * 20 + c]);
  float e[20]; float sum = 0.f;
  for (int c = 0; c < 20; ++c) { e[c] = expf(s[b * 20 + c] - mx); sum += e[c]; }
  for (int c = 0; c < 20; ++c) out[b * 20 + c] = e[c] / sum;
}

// ---------- attention scores + softmax: one wave per (call,b,h,qi) ----------
__global__ __launch_bounds__(64) void attn_scores_k(const float* __restrict__ qkvA,
                                                    const float* __restrict__ qkvB,
                                                    float* __restrict__ attnb) {
  int call = blockIdx.y;
  const float* q  = call ? qkvA : qkvB;
  const float* kv = call ? qkvB : qkvA;
  int x = blockIdx.x;
  int b = x / 148; int rem = x - b * 148; int h = rem / 37; int qi = rem - h * 37;
  int lane = threadIdx.x;
  const float scale = 0.04419417382415922f;   // 1/sqrt(512)
  const float* qp = q + ((long)(b * 37 + qi)) * 6144 + h * 512;
  float qr[8];
#pragma unroll
  for (int j = 0; j < 8; ++j) qr[j] = qp[lane + 64 * j] * scale;
  __shared__ float sc[37];
  for (int ki = 0; ki < 37; ++ki) {
    const float* kp = kv + ((long)(b * 37 + ki)) * 6144 + 2048 + h * 512;
    float d = 0.f;
#pragma unroll
    for (int j = 0; j < 8; ++j) d = fmaf(qr[j], kp[lane + 64 * j], d);
    for (int off = 32; off > 0; off >>= 1) d += __shfl_down(d, off, 64);
    if (lane == 0) sc[ki] = d;
  }
  __syncthreads();
  float v = (lane < 37) ? sc[lane] : -3.4e38f;
  float mx = v;
  for (int off = 32; off > 0; off >>= 1) mx = fmaxf(mx, __shfl_xor(mx, off, 64));
  float e = (lane < 37) ? expf(v - mx) : 0.f;
  float sum = e;
  for (int off = 32; off > 0; off >>= 1) sum += __shfl_xor(sum, off, 64);
  if (lane < 37)
    attnb[(((long)((call * 16 + b) * 4 + h)) * 37 + qi) * 37 + lane] = e / sum;
}

// ---------- attn @ V ----------
__global__ __launch_bounds__(256) void attn_v_k(const float* __restrict__ qkvA,
                                                const float* __restrict__ qkvB,
                                                const float* __restrict__ attnb,
                                                float* __restrict__ obuf) {
  int call = blockIdx.y;
  const float* kv = call ? qkvB : qkvA;
  int x = blockIdx.x;
  int b = x / 37, qi = x - b * 37;
  int tid = threadIdx.x;
  __shared__ float at[4][37];
  if (tid < 148) {
    int h = tid / 37, ki = tid - h * 37;
    at[h][ki] = attnb[(((long)((call * 16 + b) * 4 + h)) * 37 + qi) * 37 + ki];
  }
  __syncthreads();
  int yoff = call ? 37 : 0;
  float* op = obuf + ((long)(b * 74 + yoff + qi)) * 2048;
#pragma unroll
  for (int i = 0; i < 8; ++i) {
    int c = tid + 256 * i;
    int h = c >> 9;
    float acc = 0.f;
#pragma unroll 1
    for (int ki = 0; ki < 37; ++ki)
      acc = fmaf(at[h][ki], kv[((long)(b * 37 + ki)) * 6144 + 4096 + c], acc);
    op[c] = acc;
  }
}

// ---------- l1 (74->10) + leaky + l2 (320->1) + sigmoid ----------
__global__ __launch_bounds__(320) void head_tail_k(const float* __restrict__ c2o,
                                                   const float* __restrict__ l1w,
                                                   const float* __restrict__ l1b,
                                                   const float* __restrict__ l2w,
                                                   const float* __restrict__ l2b,
                                                   float* __restrict__ out) {
  __shared__ float h[320];
  int b = blockIdx.x, tid = threadIdx.x;
  int c = tid / 10, j = tid - c * 10;
  float acc = l1b[j];
  for (int l = 0; l < 74; ++l)
    acc = fmaf(c2o[((long)(b * 74 + l)) * 32 + c], l1w[j * 74 + l], acc);
  acc = leaky_f(acc);
  h[c * 10 + j] = acc * l2w[c * 10 + j];
  __syncthreads();
  if (tid == 0) {
    float s = l2b[0];
    for (int i = 0; i < 320; ++i) s += h[i];
    out[b] = 1.f / (1.f + expf(-s));
  }
}

// ---------------------------------------------------------------------------
extern "C" void kernel_launch(void* const* d_in, const int* in_sizes, int n_in,
                              void* d_out, int out_size, void* d_ws, size_t ws_size,
                              hipStream_t stream) {
  const float* x       = (const float*)d_in[0];
  const float* w_embed = (const float*)d_in[1];
  const float* b_embed = (const float*)d_in[2];
  const float* w_cls   = (const float*)d_in[3];
  const float* tf1_w   = (const float*)d_in[4];
  const float* tf1_b   = (const float*)d_in[5];
  const float* tf2_w   = (const float*)d_in[6];
  const float* tf2_b   = (const float*)d_in[7];
  const float* in_w    = (const float*)d_in[8];
  const float* in_b    = (const float*)d_in[9];
  const float* out_w   = (const float*)d_in[10];
  const float* out_b   = (const float*)d_in[11];
  const float* c1_w    = (const float*)d_in[12];
  const float* c1_b    = (const float*)d_in[13];
  const float* c2_w    = (const float*)d_in[14];
  const float* c2_b    = (const float*)d_in[15];
  const float* l1_w    = (const float*)d_in[16];
  const float* l1_b    = (const float*)d_in[17];
  const float* l2_w    = (const float*)d_in[18];
  const float* l2_b    = (const float*)d_in[19];
  float* out = (float*)d_out;
  float* ws  = (float*)d_ws;

  // output offsets (floats)
  const long O_VS = 0, O_ACT = 320, O_A2 = 12320, O_CAS = 24320, O_RH = 264320;
  const long O_EA = 264512;
  const long O_EB = O_EA + 16L * 150 * 2048;
  const long O_HA = O_EB + 16L * 150 * 2048;
  const long O_HB = O_HA + 16L * 37 * 2048;

  // workspace layout (floats)
  long o = 0;
  float* emb   = ws + o; o += 12000L * 2048;
  float* wpkE  = ws + o; o += 3L * 2048 * 2048;
  float* wpk1  = ws + o; o += 3L * 128 * 2048;
  float* wpk2  = ws + o; o += 3L * 32 * 128;
  float* qa    = ws + o; o += 592L * 6144;
  float* qb    = ws + o; o += 592L * 6144;
  float* attnb = ws + o; o += 2L * 16 * 4 * 37 * 37;
  float* obuf  = ws + o; o += 16L * 74 * 2048;
  float* ybuf  = ws + o; o += 16L * 74 * 2048;
  float* c1o   = ws + o; o += 1184L * 128;
  float* c2o   = ws + o; o += 1184L * 32;
  float* arev  = ws + o; o += 12000;
  float* hsa   = ws + o; o += 12000;
  float* hsb   = ws + o; o += 12000;
  float* med   = ws + o; o += 16;
  float* mxv   = ws + o; o += 16;
  float* vsbuf = ws + o; o += 320;
  int* idxEA = (int*)(ws + o); o += 2400;
  int* idxEB = (int*)(ws + o); o += 2400;
  int* idxHA = (int*)(ws + o); o += 592;
  int* idxHB = (int*)(ws + o); o += 592;
  (void)ws_size; (void)in_sizes; (void)n_in; (void)out_size;

  // 1. pack conv weights (n,k,tap) -> (tap,n,k)
  pack_w_k<<<(12582912 + 255) / 256, 256, 0, stream>>>(w_embed, wpkE, 2048, 2048, 3);
  pack_w_k<<<(786432 + 255) / 256, 256, 0, stream>>>(c1_w, wpk1, 128, 2048, 3);
  pack_w_k<<<(12288 + 255) / 256, 256, 0, stream>>>(c2_w, wpk2, 32, 128, 3);

  // 2. embed conv (k3, 2048->2048) + relu — fp64 tile accumulation
  gemm64_k<1><<<dim3(32, 188), 256, 0, stream>>>(x, wpkE, b_embed, emb,
      12000, 2048, 2048, 3, -1, 750, 1536000L, 750, 1536000L, 1);

  // 3. cas (1x1, 2048->20) + relu — fp64 tile accumulation
  gemm32_k<1><<<dim3(1, 375), 256, 0, stream>>>(emb, w_cls, nullptr, out + O_CAS,
      12000, 20, 2048, 1, 0, 750, 1536000L, 750, 15000L, 1);

  // 4. actionness, a2
  actionness_k<<<47, 256, 0, stream>>>(out + O_CAS, out + O_ACT);
  a2_k<<<16, 256, 0, stream>>>(out + O_ACT, tf1_w, tf1_b, tf2_w, tf2_b, out + O_A2);

  // 5. video scores
  vtop_k<<<320, 256, 0, stream>>>(out + O_CAS, vsbuf);
  softmax20_k<<<16, 64, 0, stream>>>(vsbuf, out + O_VS);

  // 6. selections
  sort_topk_k<<<16, 256, 0, stream>>>(out + O_ACT, idxEA, 150, med, mxv);
  morph_k<<<16, 256, 0, stream>>>(out + O_ACT, med, mxv, arev, hsa, hsb);
  sort_topk_k<<<16, 256, 0, stream>>>(arev, idxEB, 150, nullptr, nullptr);
  sort_topk_k<<<16, 256, 0, stream>>>(hsa, idxHA, 37, nullptr, nullptr);
  sort_topk_k<<<16, 256, 0, stream>>>(hsb, idxHB, 37, nullptr, nullptr);

  gather_k<<<2400, 256, 0, stream>>>(emb, idxEA, out + O_EA, 150);
  gather_k<<<2400, 256, 0, stream>>>(emb, idxEB, out + O_EB, 150);
  gather_k<<<592, 256, 0, stream>>>(emb, idxHA, out + O_HA, 37);
  gather_k<<<592, 256, 0, stream>>>(emb, idxHB, out + O_HB, 37);

  // 7. relational heads
  struct RhIn { const float* base; long bstride; };
  const long ES = 150L * 2048, HS = 37L * 2048;
  RhIn ea0{out + O_EA,               ES}, ea1{out + O_EA + 37L * 2048, ES},
       ea2{out + O_EA + 74L * 2048, ES}, ea3{out + O_EA + 111L * 2048, ES};
  RhIn eb0{out + O_EB,               ES}, eb1{out + O_EB + 37L * 2048, ES},
       eb2{out + O_EB + 74L * 2048, ES}, eb3{out + O_EB + 111L * 2048, ES};
  RhIn hA{out + O_HA, HS}, hB{out + O_HB, HS};

  RhIn tbl[12][2] = {
    {ea1, hA},  // re_a_0h
    {ea3, ea2}, // re_a_02
    {ea0, ea3}, // re_a_03
    {eb1, hB},  // re_b_0h
    {eb3, eb2}, // re_b_02
    {eb0, eb3}, // re_b_03
    {hB, hA},   // re_ab_hh
    {ea3, hB},  // re_ab_3h
    {hA, eb3},  // re_ab_h3
    {ea3, eb3}, // re_ab_33
    {eb2, ea3}, // re_ab_32
    {ea2, eb3}, // re_ab_23
  };

  for (int i = 0; i < 12; ++i) {
    const RhIn& A = tbl[i][0];
    const RhIn& Bv = tbl[i][1];
    gemm64_k<0><<<dim3(96, 10), 256, 0, stream>>>(A.base, in_w, in_b, qa,
        592, 6144, 2048, 1, 0, 37, A.bstride, 37, 37L * 6144, 0);
    gemm64_k<0><<<dim3(96, 10), 256, 0, stream>>>(Bv.base, in_w, in_b, qb,
        592, 6144, 2048, 1, 0, 37, Bv.bstride, 37, 37L * 6144, 0);
    attn_scores_k<<<dim3(2368, 2), 64, 0, stream>>>(qa, qb, attnb);
    attn_v_k<<<dim3(592, 2), 256, 0, stream>>>(qa, qb, attnb, obuf);
    gemm64_k<0><<<dim3(32, 19), 256, 0, stream>>>(obuf, out_w, out_b, ybuf,
        1184, 2048, 2048, 1, 0, 74, 74L * 2048, 74, 74L * 2048, 0);
    gemm32_k<0><<<dim3(4, 37), 256, 0, stream>>>(ybuf, wpk1, c1_b, c1o,
        1184, 128, 2048, 3, -1, 74, 74L * 2048, 74, 74L * 128, 2);
    gemm32_k<0><<<dim3(1, 37), 256, 0, stream>>>(c1o, wpk2, c2_b, c2o,
        1184, 32, 128, 3, -1, 74, 74L * 128, 74, 74L * 32, 2);
    head_tail_k<<<16, 320, 0, stream>>>(c2o, l1_w, l1_b, l2_w, l2_b, out + O_RH + 16L * i);
  }
}